// Round 4
// baseline (345.238 us; speedup 1.0000x reference)
//
#include <hip/hip_runtime.h>
#include <hip/hip_cooperative_groups.h>
#include <math.h>

namespace cg = cooperative_groups;

#define B_ 4
#define N_ 20000
#define M_ 1024
#define K_ 16384
#define D_ 768

typedef __attribute__((ext_vector_type(8))) short bf16x8;
typedef __attribute__((ext_vector_type(4))) float f32x4;

// Workspace offsets
#define OFF_PART   0ul          // f32 [4][16][3]
#define OFF_RAD    1024ul       // f32 [4][16]
#define OFF_IDX    4096ul       // int [4][1024]
#define OFF_G      2097152ul    // f32 [4][768][1024]
#define OFF_XLN    16777216ul   // bf16 [4096][768]
#define OFF_FUSED  25165824ul   // bf16 [4096][512]
#define OFF_H2     29360128ul   // bf16 [4096][256]
#define OFF_WB1    33554432ul   // bf16 [256][768]
#define OFF_WCAT   34603008ul   // bf16 [256][512]
#define OFF_WB4    35651584ul   // bf16 [256][256]
#define OFF_BC     36700160ul   // f32 [256]

__device__ inline unsigned short f2bf(float x) {
    union { float f; unsigned int u; } v; v.f = x;
    unsigned int r = v.u + 0x7fffu + ((v.u >> 16) & 1u);
    return (unsigned short)(r >> 16);
}

__device__ inline void gload_lds16(const void* g, void* lds) {
    __builtin_amdgcn_global_load_lds(
        (const __attribute__((address_space(1))) unsigned int*)g,
        (__attribute__((address_space(3))) unsigned int*)lds, 16, 0, 0);
}

struct MegaArgs {
    const float *pc, *seed_xyz, *sf, *pts, *feat, *ln_g, *ln_b;
    const float *pw1, *pb1, *pw2, *pb2, *fw1, *fb1, *fw2, *fb2;
    float *part; float *rad; int *idx; float *G;
    unsigned short *xln, *fused, *h2, *Wb1, *Wcat, *Wb4;
    float *bc; float *out;
};

__device__ inline void reduce_center(const float* part, int b,
                                     float& cx, float& cy, float& cz)
{
    cx = 0.f; cy = 0.f; cz = 0.f;
    #pragma unroll
    for (int r = 0; r < 16; ++r) {
        cx += part[(b*16+r)*3+0];
        cy += part[(b*16+r)*3+1];
        cz += part[(b*16+r)*3+2];
    }
    cx *= (1.f/N_); cy *= (1.f/N_); cz *= (1.f/N_);
}

__device__ inline float reduce_scale(const float* rad, int b)
{
    float m = 0.f;
    #pragma unroll
    for (int r = 0; r < 16; ++r) m = fmaxf(m, rad[b*16+r]);
    return fmaxf(sqrtf(m), 1e-6f);
}

// GEMM phase (port of round-1/3 verified k_gemm_mfma; bid -> (m0,o0))
__device__ void gemm_phase(const unsigned short* X, const unsigned short* W,
                           const float* bias, int Kdim, int relu, int mode,
                           unsigned short* Ybf, int rowStride, int colOff,
                           float* Yf, char* smem, int bid, int t)
{
    unsigned short* Al = (unsigned short*)smem;
    unsigned short* Wl = (unsigned short*)(smem + 8192);
    int l = t & 63, w = t >> 6;
    int m0 = (bid & 63) * 64, o0 = (bid >> 6) * 64;
    f32x4 acc[4];
    #pragma unroll
    for (int j = 0; j < 4; ++j) acc[j] = (f32x4){0.f, 0.f, 0.f, 0.f};

    for (int kc = 0; kc < Kdim; kc += 64) {
        #pragma unroll
        for (int i = 0; i < 2; ++i) {
            int lin = i*4096 + w*1024;
            int lb  = lin + l*16;
            int row = lb >> 7;
            int k16 = (lb >> 4) & 7;
            int ks  = k16 ^ (row & 7);
            gload_lds16(X + (size_t)(m0+row)*Kdim + kc + ks*8, (char*)Al + lin);
            gload_lds16(W + (size_t)(o0+row)*Kdim + kc + ks*8, (char*)Wl + lin);
        }
        __syncthreads();
        #pragma unroll
        for (int kk = 0; kk < 2; ++kk) {
            int arow = w*16 + (l & 15);
            int h = l >> 4;
            bf16x8 a = *(const bf16x8*)&Al[arow*64 + (((kk<<2)|h) ^ (arow & 7))*8];
            #pragma unroll
            for (int j = 0; j < 4; ++j) {
                int orow = j*16 + (l & 15);
                bf16x8 bfr = *(const bf16x8*)&Wl[orow*64 + (((kk<<2)|h) ^ (orow & 7))*8];
                acc[j] = __builtin_amdgcn_mfma_f32_16x16x32_bf16(a, bfr, acc[j], 0, 0, 0);
            }
        }
        __syncthreads();
    }

    int mbase = m0 + w*16 + (l >> 4)*4;
    if (mode == 0) {
        #pragma unroll
        for (int j = 0; j < 4; ++j) {
            int o = o0 + j*16 + (l & 15);
            float bi = bias[o];
            #pragma unroll
            for (int r = 0; r < 4; ++r) {
                float v = acc[j][r] + bi;
                if (relu) v = fmaxf(v, 0.f);
                Ybf[(size_t)(mbase + r)*rowStride + colOff + o] = f2bf(v);
            }
        }
    } else {
        int b = mbase >> 10, ml = mbase & 1023;
        #pragma unroll
        for (int j = 0; j < 4; ++j) {
            int o = o0 + j*16 + (l & 15);
            float bi = bias[o];
            float4 sv = make_float4(acc[j][0]+bi, acc[j][1]+bi, acc[j][2]+bi, acc[j][3]+bi);
            *(float4*)&Yf[((size_t)(b*256 + o))*1024 + ml] = sv;
        }
    }
}

__global__ __launch_bounds__(256) void k_mega(MegaArgs a)
{
    __shared__ __align__(16) char smem[52224];   // max: LN tile 768*17*4
    __shared__ float sred[16][16];
    __shared__ float qred[16][16];
    __shared__ float smu[16], siv[16];
    __shared__ float wred[4];
    __shared__ float csred[3][4];

    cg::grid_group grid = cg::this_grid();
    int bid = blockIdx.x, t = threadIdx.x;
    int lane = t & 63, wv = t >> 6;

    // ---------------- Phase 0: cvt + wc + cs_sum + transpose_sf -------------
    {   // (a) weight conversions
        int i0 = bid*256 + t;
        for (int i = i0; i < 256*768; i += 65536) a.Wb1[i] = f2bf(a.pw1[i]);
        int o = i0 >> 8, c = i0 & 255;
        a.Wcat[(size_t)o*512 + c] = f2bf(a.fw1[(size_t)o*512 + c]);
        a.Wb4[i0] = f2bf(a.fw2[i0]);
    }
    {   // (b) Wcat[:,256:512] = bf16(fw1b @ pw2); bc = fw1b@pb2 + fb1  (o=bid)
        const float* fb = a.fw1 + (size_t)bid*512 + 256;
        float acc = 0.f;
        for (int j = 0; j < 256; ++j)
            acc = fmaf(fb[j], a.pw2[j*256 + t], acc);
        a.Wcat[(size_t)bid*512 + 256 + t] = f2bf(acc);
        float v = fb[t] * a.pb2[t];
        for (int off = 32; off; off >>= 1) v += __shfl_down(v, off, 64);
        if (!lane) wred[wv] = v;
        __syncthreads();
        if (!t) a.bc[bid] = wred[0]+wred[1]+wred[2]+wred[3] + a.fb1[bid];
    }
    if (bid < 64) {   // (c) cs_sum partials
        int b = bid >> 4, pi = bid & 15;
        const float* p = a.pc + (size_t)b * N_ * 3;
        int i0 = pi * 1250;
        float sx = 0.f, sy = 0.f, sz = 0.f;
        for (int i = i0 + t; i < i0 + 1250; i += 256) {
            sx += p[i*3+0]; sy += p[i*3+1]; sz += p[i*3+2];
        }
        for (int off = 32; off; off >>= 1) {
            sx += __shfl_down(sx, off, 64);
            sy += __shfl_down(sy, off, 64);
            sz += __shfl_down(sz, off, 64);
        }
        if (!lane) { csred[0][wv] = sx; csred[1][wv] = sy; csred[2][wv] = sz; }
        __syncthreads();
        if (!t) {
            a.part[(b*16+pi)*3+0] = csred[0][0]+csred[0][1]+csred[0][2]+csred[0][3];
            a.part[(b*16+pi)*3+1] = csred[1][0]+csred[1][1]+csred[1][2]+csred[1][3];
            a.part[(b*16+pi)*3+2] = csred[2][0]+csred[2][1]+csred[2][2]+csred[2][3];
        }
    }
    {   // (d) seed_features transpose -> fused[:, 0:256] bf16 (4 tiles/block)
        float (*tile)[33] = (float(*)[33])smem;
        int tx = t & 31, ty = t >> 5;
        for (int r = 0; r < 4; ++r) {
            int id = bid*4 + r;
            int b = id >> 8, rem = id & 255;
            int m0 = (rem & 31) * 32, c0 = (rem >> 5) * 32;
            __syncthreads();
            #pragma unroll
            for (int rr = 0; rr < 32; rr += 8)
                tile[ty+rr][tx] = a.sf[((size_t)b*256 + c0+ty+rr)*M_ + m0 + tx];
            __syncthreads();
            #pragma unroll
            for (int rr = 0; rr < 32; rr += 8)
                a.fused[((size_t)(b*M_ + m0+ty+rr))*512 + c0 + tx] = f2bf(tile[tx][ty+rr]);
        }
    }
    grid.sync();

    // ---------------- Phase 1: cs_rad ---------------------------------------
    if (bid < 64) {
        int b = bid >> 4, pi = bid & 15;
        float cx, cy, cz;
        reduce_center(a.part, b, cx, cy, cz);
        const float* p = a.pc + (size_t)b * N_ * 3;
        int i0 = pi * 1250;
        float mx = 0.f;
        for (int i = i0 + t; i < i0 + 1250; i += 256) {
            float dx = p[i*3+0]-cx, dy = p[i*3+1]-cy, dz = p[i*3+2]-cz;
            mx = fmaxf(mx, dx*dx + dy*dy + dz*dz);
        }
        for (int off = 32; off; off >>= 1) mx = fmaxf(mx, __shfl_down(mx, off, 64));
        if (!lane) wred[wv] = mx;
        __syncthreads();
        if (!t) a.rad[b*16+pi] = fmaxf(fmaxf(wred[0], wred[1]), fmaxf(wred[2], wred[3]));
    }
    grid.sync();

    // ---------------- Phase 2: NN argmin (normalize at stage time) ----------
    {
        int b = bid >> 6, sgrp = bid & 63;
        float cx, cy, cz;
        reduce_center(a.part, b, cx, cy, cz);
        float scinv = 1.f / reduce_scale(a.rad, b);
        int j = t & 15, s = t >> 4;
        int m = sgrp*16 + s;
        const float* sp = a.seed_xyz + ((size_t)b*M_ + m)*3;
        float sx = (sp[0]-cx)*scinv, sy = (sp[1]-cy)*scinv, sz = (sp[2]-cz)*scinv;
        float ssq = sx*sx + sy*sy + sz*sz;
        const float* pb = a.pts + (size_t)b*K_*3;
        float4* P = (float4*)smem;    // 1024 float4 = 16 KB

        float bestv[4] = {3.4e38f, 3.4e38f, 3.4e38f, 3.4e38f};
        int   bestk[4] = {0, 0, 0, 0};
        for (int c0 = 0; c0 < K_; c0 += 1024) {
            __syncthreads();
            #pragma unroll
            for (int r = 0; r < 4; ++r) {
                int k = c0 + r*256 + t;
                const float* pp = pb + (size_t)k*3;
                float px = (pp[0]-cx)*scinv, py = (pp[1]-cy)*scinv, pz = (pp[2]-cz)*scinv;
                P[r*256+t] = make_float4(px, py, pz, px*px + py*py + pz*pz);
            }
            __syncthreads();
            for (int u = 0; u < 64; u += 4) {
                #pragma unroll
                for (int r = 0; r < 4; ++r) {
                    int ti = (u+r)*16 + j;
                    float4 q = P[ti];
                    float d2 = ssq + q.w - 2.f*(sx*q.x + sy*q.y + sz*q.z);
                    int k = c0 + ti;
                    if (d2 < bestv[r]) { bestv[r] = d2; bestk[r] = k; }
                }
            }
        }
        float bm = bestv[0]; int bmk = bestk[0];
        #pragma unroll
        for (int r = 1; r < 4; ++r)
            if (bestv[r] < bm || (bestv[r] == bm && bestk[r] < bmk)) { bm = bestv[r]; bmk = bestk[r]; }
        #pragma unroll
        for (int mask = 8; mask; mask >>= 1) {
            float ob = __shfl_xor(bm, mask, 64);
            int   ok = __shfl_xor(bmk, mask, 64);
            if (ob < bm || (ob == bm && ok < bmk)) { bm = ob; bmk = ok; }
        }
        if (j == 0) a.idx[b*M_ + m] = bmk;
    }
    grid.sync();

    // ---------------- Phase 3: gather (12 rows per block) -------------------
    {
        for (int u = 0; u < 12; ++u) {
            int row = bid*12 + u;          // 0..3071
            int b = row / 768, c = row - b*768;
            const float* frow = a.feat + ((size_t)b*D_ + c) * K_;
            const int* ib = a.idx + b*M_;
            float* grow = a.G + ((size_t)b*D_ + c) * M_;
            #pragma unroll
            for (int r = 0; r < 4; ++r) {
                int m = r*256 + t;
                grow[m] = frow[ib[m]];
            }
        }
    }
    grid.sync();

    // ---------------- Phase 4: LN (single pass, tile LDS-resident) ----------
    {
        int b = bid >> 6, m0 = (bid & 63) * 16;
        const float* Gb = a.G + (size_t)b * D_ * M_;
        float (*L)[17] = (float(*)[17])smem;   // [768][17] pad
        #pragma unroll 4
        for (int u = 0; u < 48; ++u) {
            int lin = u*256 + t;
            int c = lin >> 4, ml = lin & 15;
            L[c][ml] = Gb[(size_t)c*M_ + m0 + ml];
        }
        __syncthreads();
        int m = t & 15, seg = t >> 4;
        float s = 0.f, q = 0.f;
        for (int i = 0; i < 48; ++i) {
            float v = L[seg*48 + i][m];
            s += v; q += v*v;
        }
        sred[seg][m] = s; qred[seg][m] = q;
        __syncthreads();
        if (t < 16) {
            float S = 0.f, Q = 0.f;
            #pragma unroll
            for (int r = 0; r < 16; ++r) { S += sred[r][t]; Q += qred[r][t]; }
            float mu = S * (1.f/768.f);
            smu[t] = mu;
            siv[t] = rsqrtf(Q * (1.f/768.f) - mu*mu + 1e-5f);
        }
        __syncthreads();
        float mu = smu[m], iv = siv[m];
        size_t orow = ((size_t)(b*M_ + m0 + m)) * D_;
        for (int i = 0; i < 48; i += 2) {
            int c = seg*48 + i;
            float v0 = (L[c][m]   - mu) * iv * a.ln_g[c]   + a.ln_b[c];
            float v1 = (L[c+1][m] - mu) * iv * a.ln_g[c+1] + a.ln_b[c+1];
            ushort2 pk = make_ushort2(f2bf(v0), f2bf(v1));
            *(ushort2*)&a.xln[orow + c] = pk;
        }
    }
    grid.sync();

    // ---------------- Phase 5: gemm1 -> fused[:,256:512] --------------------
    gemm_phase(a.xln, a.Wb1, a.pb1, 768, 1, 0, a.fused, 512, 256, nullptr, smem, bid, t);
    grid.sync();

    // ---------------- Phase 6: gemm3' -> h2 ---------------------------------
    gemm_phase(a.fused, a.Wcat, a.bc, 512, 1, 0, a.h2, 256, 0, nullptr, smem, bid, t);
    grid.sync();

    // ---------------- Phase 7: gemm4 -> out (f32 [B][256][M]) ---------------
    gemm_phase(a.h2, a.Wb4, a.fb2, 256, 0, 1, nullptr, 0, 0, a.out, smem, bid, t);
}

// ---------------------------------------------------------------------------
extern "C" void kernel_launch(void* const* d_in, const int* in_sizes, int n_in,
                              void* d_out, int out_size, void* d_ws, size_t ws_size,
                              hipStream_t stream)
{
    (void)in_sizes; (void)n_in; (void)out_size; (void)ws_size;
    char* ws = (char*)d_ws;
    MegaArgs a;
    a.pc       = (const float*)d_in[0];
    a.seed_xyz = (const float*)d_in[1];
    a.sf       = (const float*)d_in[2];
    a.pts      = (const float*)d_in[3];
    a.feat     = (const float*)d_in[4];
    a.ln_g     = (const float*)d_in[5];
    a.ln_b     = (const float*)d_in[6];
    a.pw1      = (const float*)d_in[7];
    a.pb1      = (const float*)d_in[8];
    a.pw2      = (const float*)d_in[9];
    a.pb2      = (const float*)d_in[10];
    a.fw1      = (const float*)d_in[11];
    a.fb1      = (const float*)d_in[12];
    a.fw2      = (const float*)d_in[13];
    a.fb2      = (const float*)d_in[14];
    a.part  = (float*)(ws + OFF_PART);
    a.rad   = (float*)(ws + OFF_RAD);
    a.idx   = (int*)(ws + OFF_IDX);
    a.G     = (float*)(ws + OFF_G);
    a.xln   = (unsigned short*)(ws + OFF_XLN);
    a.fused = (unsigned short*)(ws + OFF_FUSED);
    a.h2    = (unsigned short*)(ws + OFF_H2);
    a.Wb1   = (unsigned short*)(ws + OFF_WB1);
    a.Wcat  = (unsigned short*)(ws + OFF_WCAT);
    a.Wb4   = (unsigned short*)(ws + OFF_WB4);
    a.bc    = (float*)(ws + OFF_BC);
    a.out   = (float*)d_out;

    void* kargs[] = { &a };
    hipLaunchCooperativeKernel((const void*)k_mega, dim3(256), dim3(256),
                               kargs, 0, stream);
}

// Round 5
// 163.655 us; speedup vs baseline: 2.1096x; 2.1096x over previous
//
#include <hip/hip_runtime.h>
#include <math.h>

#define B_ 4
#define N_ 20000
#define M_ 1024
#define K_ 16384
#define D_ 768

typedef __attribute__((ext_vector_type(8))) short bf16x8;
typedef __attribute__((ext_vector_type(4))) float f32x4;

// Workspace offsets (ws is 768 MiB)
#define OFF_PART   0ul          // f32 [4][16][3] partial sums
#define OFF_RAD    1024ul       // f32 [4][16] partial max radius^2
#define OFF_IDX    4096ul       // int [4][1024]
#define OFF_G      2097152ul    // f32 [4][768][1024]  (12.58 MB)
#define OFF_XLN    16777216ul   // bf16 [4096][768]
#define OFF_FUSED  25165824ul   // bf16 [4096][512]
#define OFF_H2     29360128ul   // bf16 [4096][256]
#define OFF_WB1    33554432ul   // bf16 [256][768]
#define OFF_WCAT   34603008ul   // bf16 [256][512]
#define OFF_WB4    35651584ul   // bf16 [256][256]
#define OFF_BC     36700160ul   // f32 [256]

__device__ inline unsigned short f2bf(float x) {
    union { float f; unsigned int u; } v; v.f = x;
    unsigned int r = v.u + 0x7fffu + ((v.u >> 16) & 1u);
    return (unsigned short)(r >> 16);
}

__device__ inline void gload_lds16(const void* g, void* lds) {
    __builtin_amdgcn_global_load_lds(
        (const __attribute__((address_space(1))) unsigned int*)g,
        (__attribute__((address_space(3))) unsigned int*)lds, 16, 0, 0);
}

__device__ inline void reduce_center(const float* part, int b,
                                     float& cx, float& cy, float& cz)
{
    cx = 0.f; cy = 0.f; cz = 0.f;
    #pragma unroll
    for (int r = 0; r < 16; ++r) {
        cx += part[(b*16+r)*3+0];
        cy += part[(b*16+r)*3+1];
        cz += part[(b*16+r)*3+2];
    }
    cx *= (1.f/N_); cy *= (1.f/N_); cz *= (1.f/N_);
}

__device__ inline float reduce_scale(const float* rad, int b)
{
    float m = 0.f;
    #pragma unroll
    for (int r = 0; r < 16; ++r) m = fmaxf(m, rad[b*16+r]);
    return fmaxf(sqrtf(m), 1e-6f);
}

// ---------------------------------------------------------------------------
// k_pre: weight cvt (bid<768) + Wcat-fold/bc (bid<256) + cs_sum (bid>=768)
__global__ __launch_bounds__(256) void k_pre(
    const float* __restrict__ pc,
    const float* __restrict__ pw1, const float* __restrict__ pw2,
    const float* __restrict__ pb2,
    const float* __restrict__ fw1, const float* __restrict__ fb1,
    const float* __restrict__ fw2,
    unsigned short* __restrict__ Wb1, unsigned short* __restrict__ Wcat,
    unsigned short* __restrict__ Wb4, float* __restrict__ bc,
    float* __restrict__ part)
{
    int bid = blockIdx.x, t = threadIdx.x;
    int lane = t & 63, wv = t >> 6;
    __shared__ float red[3][4];

    if (bid < 768) {
        int i0 = bid*256 + t;
        Wb1[i0] = f2bf(pw1[i0]);
        if (i0 < 65536) {
            int o = i0 >> 8, c = i0 & 255;
            Wcat[(size_t)o*512 + c] = f2bf(fw1[(size_t)o*512 + c]);
            Wb4[i0] = f2bf(fw2[i0]);
        }
    }
    if (bid < 256) {
        // Wcat[:,256:512] = bf16(fw1b @ pw2); bc = fw1b@pb2 + fb1 (o=bid)
        const float* fb = fw1 + (size_t)bid*512 + 256;
        float acc = 0.f;
        for (int j = 0; j < 256; ++j)
            acc = fmaf(fb[j], pw2[j*256 + t], acc);
        Wcat[(size_t)bid*512 + 256 + t] = f2bf(acc);
        float v = fb[t] * pb2[t];
        for (int off = 32; off; off >>= 1) v += __shfl_down(v, off, 64);
        if (!lane) red[0][wv] = v;
        __syncthreads();
        if (!t) bc[bid] = red[0][0]+red[0][1]+red[0][2]+red[0][3] + fb1[bid];
    } else if (bid >= 768) {
        // cs_sum partials
        int pi = bid - 768;
        int b = pi >> 4, chunk = pi & 15;
        const float* p = pc + (size_t)b * N_ * 3;
        int i0 = chunk * 1250;
        float sx = 0.f, sy = 0.f, sz = 0.f;
        for (int i = i0 + t; i < i0 + 1250; i += 256) {
            sx += p[i*3+0]; sy += p[i*3+1]; sz += p[i*3+2];
        }
        for (int off = 32; off; off >>= 1) {
            sx += __shfl_down(sx, off, 64);
            sy += __shfl_down(sy, off, 64);
            sz += __shfl_down(sz, off, 64);
        }
        if (!lane) { red[0][wv] = sx; red[1][wv] = sy; red[2][wv] = sz; }
        __syncthreads();
        if (!t) {
            part[(b*16+chunk)*3+0] = red[0][0]+red[0][1]+red[0][2]+red[0][3];
            part[(b*16+chunk)*3+1] = red[1][0]+red[1][1]+red[1][2]+red[1][3];
            part[(b*16+chunk)*3+2] = red[2][0]+red[2][1]+red[2][2]+red[2][3];
        }
    }
}

// ---------------------------------------------------------------------------
__global__ __launch_bounds__(256) void k_cs_rad(const float* __restrict__ pc,
                                                const float* __restrict__ part,
                                                float* __restrict__ rad)
{
    int blk = blockIdx.x, b = blk >> 4, pi = blk & 15;
    float cx, cy, cz;
    reduce_center(part, b, cx, cy, cz);
    const float* p = pc + (size_t)b * N_ * 3;
    int tid = threadIdx.x;
    int i0 = pi * 1250;
    float mx = 0.f;
    for (int i = i0 + tid; i < i0 + 1250; i += 256) {
        float dx = p[i*3+0]-cx, dy = p[i*3+1]-cy, dz = p[i*3+2]-cz;
        mx = fmaxf(mx, dx*dx + dy*dy + dz*dz);
    }
    for (int off = 32; off; off >>= 1) mx = fmaxf(mx, __shfl_down(mx, off, 64));
    __shared__ float red[4];
    int w = tid >> 6, l = tid & 63;
    if (!l) red[w] = mx;
    __syncthreads();
    if (!tid) rad[b*16+pi] = fmaxf(fmaxf(red[0], red[1]), fmaxf(red[2], red[3]));
}

// ---------------------------------------------------------------------------
// NN argmin: 512 blocks; block = 8 seeds x 32 lanes, normalize pts inline
// (identical arithmetic to round-3 prep+nn: (p-c)*scinv, psq, d2)
__global__ __launch_bounds__(256) void k_nn(const float* __restrict__ seed_xyz,
                                            const float* __restrict__ pts,
                                            const float* __restrict__ part,
                                            const float* __restrict__ rad,
                                            int* __restrict__ idx)
{
    int blk = blockIdx.x, b = blk >> 7, g = blk & 127;
    float cx, cy, cz;
    reduce_center(part, b, cx, cy, cz);
    float scinv = 1.f / reduce_scale(rad, b);
    int t = threadIdx.x;
    int j = t & 31, s = t >> 5;
    int m = g*8 + s;
    const float* sp = seed_xyz + ((size_t)b*M_ + m)*3;
    float sx = (sp[0]-cx)*scinv, sy = (sp[1]-cy)*scinv, sz = (sp[2]-cz)*scinv;
    float ssq = sx*sx + sy*sy + sz*sz;
    const float* pb = pts + (size_t)b*K_*3;

    float best[4] = {3.4e38f, 3.4e38f, 3.4e38f, 3.4e38f};
    int   bk[4]   = {0, 0, 0, 0};
    for (int i = 0; i < 512; i += 4) {
        #pragma unroll
        for (int r = 0; r < 4; ++r) {
            int k = (i + r)*32 + j;
            const float* pp = pb + (size_t)k*3;
            float px = (pp[0]-cx)*scinv, py = (pp[1]-cy)*scinv, pz = (pp[2]-cz)*scinv;
            float qw = px*px + py*py + pz*pz;
            float d2 = ssq + qw - 2.f*(sx*px + sy*py + sz*pz);
            if (d2 < best[r]) { best[r] = d2; bk[r] = k; }
        }
    }
    float bm = best[0]; int bmk = bk[0];
    #pragma unroll
    for (int r = 1; r < 4; ++r) {
        if (best[r] < bm || (best[r] == bm && bk[r] < bmk)) { bm = best[r]; bmk = bk[r]; }
    }
    #pragma unroll
    for (int mask = 16; mask; mask >>= 1) {
        float ob = __shfl_xor(bm, mask, 64);
        int   ok = __shfl_xor(bmk, mask, 64);
        if (ob < bm || (ob == bm && ok < bmk)) { bm = ob; bmk = ok; }
    }
    if (j == 0) idx[b*M_ + m] = bmk;
}

// ---------------------------------------------------------------------------
// gather (bid<3072: one (b,c) row each) + seed-feature transpose (bid>=3072)
__global__ __launch_bounds__(256) void k_gather_tsf(const float* __restrict__ feat,
                                                    const int* __restrict__ idx,
                                                    const float* __restrict__ sf,
                                                    float* __restrict__ G,
                                                    unsigned short* __restrict__ fused)
{
    int bid = blockIdx.x, t = threadIdx.x;
    if (bid < 3072) {
        int b = bid / 768, c = bid - b*768;
        const float* frow = feat + ((size_t)b*D_ + c) * K_;
        const int* ib = idx + b*M_;
        float* grow = G + ((size_t)b*D_ + c) * M_;
        #pragma unroll
        for (int r = 0; r < 4; ++r) {
            int m = r*256 + t;
            grow[m] = frow[ib[m]];
        }
    } else {
        __shared__ float tile[32][33];
        int id = bid - 3072;               // 0..1023
        int b = id >> 8, rem = id & 255;
        int m0 = (rem & 31) * 32, c0 = (rem >> 5) * 32;
        int tx = t & 31, ty = t >> 5;
        #pragma unroll
        for (int rr = 0; rr < 32; rr += 8)
            tile[ty+rr][tx] = sf[((size_t)b*256 + c0+ty+rr)*M_ + m0 + tx];
        __syncthreads();
        #pragma unroll
        for (int rr = 0; rr < 32; rr += 8)
            fused[((size_t)(b*M_ + m0+ty+rr))*512 + c0 + tx] = f2bf(tile[tx][ty+rr]);
    }
}

// ---------------------------------------------------------------------------
// fused LN: stats + apply + transpose -> xln bf16 [b][m][c]  (round-3 verified)
__global__ __launch_bounds__(256) void k_ln_fused(const float* __restrict__ G,
                                                  const float* __restrict__ gamma,
                                                  const float* __restrict__ beta,
                                                  unsigned short* __restrict__ xln)
{
    int b = blockIdx.y, m0 = blockIdx.x * 32;
    int t = threadIdx.x;
    int ml = t & 31, cp = t >> 5;
    const float* Gb = G + (size_t)b * D_ * M_;
    float s = 0.f, q = 0.f;
    for (int c = cp; c < D_; c += 8) {
        float v = Gb[(size_t)c*M_ + m0 + ml];
        s += v; q += v*v;
    }
    __shared__ float sred[8][32], qred[8][32];
    __shared__ float mu[32], iv[32];
    sred[cp][ml] = s; qred[cp][ml] = q;
    __syncthreads();
    if (t < 32) {
        float S = 0.f, Q = 0.f;
        #pragma unroll
        for (int r = 0; r < 8; ++r) { S += sred[r][t]; Q += qred[r][t]; }
        float m_ = S * (1.f/768.f);
        mu[t] = m_;
        iv[t] = rsqrtf(Q * (1.f/768.f) - m_*m_ + 1e-5f);
    }
    __syncthreads();

    __shared__ float tile[64][33];
    int ty = t >> 5;
    int cx2 = t & 31;
    for (int c0 = 0; c0 < D_; c0 += 64) {
        __syncthreads();
        #pragma unroll
        for (int ri = 0; ri < 8; ++ri) {
            int cl = ty*8 + ri;
            tile[cl][ml] = Gb[(size_t)(c0+cl)*M_ + m0 + ml];
        }
        __syncthreads();
        float2 ga = *(const float2*)&gamma[c0 + 2*cx2];
        float2 be = *(const float2*)&beta[c0 + 2*cx2];
        #pragma unroll
        for (int ri = 0; ri < 4; ++ri) {
            int m_l = ty*4 + ri;
            float v0 = (tile[2*cx2+0][m_l] - mu[m_l]) * iv[m_l] * ga.x + be.x;
            float v1 = (tile[2*cx2+1][m_l] - mu[m_l]) * iv[m_l] * ga.y + be.y;
            ushort2 pk = make_ushort2(f2bf(v0), f2bf(v1));
            *(ushort2*)&xln[((size_t)((b<<10) + m0 + m_l))*D_ + c0 + 2*cx2] = pk;
        }
    }
}

// ---------------------------------------------------------------------------
// MFMA GEMM (round-1/3 verified)
__global__ __launch_bounds__(256) void k_gemm_mfma(
    const unsigned short* __restrict__ X, const unsigned short* __restrict__ W,
    const float* __restrict__ bias, int Kdim, int relu, int mode,
    unsigned short* __restrict__ Ybf, int rowStride, int colOff,
    float* __restrict__ Yf)
{
    __shared__ unsigned short Al[64*64];
    __shared__ unsigned short Wl[64*64];
    int t = threadIdx.x, l = t & 63, w = t >> 6;
    int m0 = blockIdx.x * 64, o0 = blockIdx.y * 64;
    f32x4 acc[4];
    #pragma unroll
    for (int j = 0; j < 4; ++j) acc[j] = (f32x4){0.f, 0.f, 0.f, 0.f};

    for (int kc = 0; kc < Kdim; kc += 64) {
        #pragma unroll
        for (int i = 0; i < 2; ++i) {
            int lin = i*4096 + w*1024;
            int lb  = lin + l*16;
            int row = lb >> 7;
            int k16 = (lb >> 4) & 7;
            int ks  = k16 ^ (row & 7);
            gload_lds16(X + (size_t)(m0+row)*Kdim + kc + ks*8, (char*)Al + lin);
            gload_lds16(W + (size_t)(o0+row)*Kdim + kc + ks*8, (char*)Wl + lin);
        }
        __syncthreads();
        #pragma unroll
        for (int kk = 0; kk < 2; ++kk) {
            int arow = w*16 + (l & 15);
            int h = l >> 4;
            bf16x8 a = *(const bf16x8*)&Al[arow*64 + (((kk<<2)|h) ^ (arow & 7))*8];
            #pragma unroll
            for (int j = 0; j < 4; ++j) {
                int orow = j*16 + (l & 15);
                bf16x8 bfr = *(const bf16x8*)&Wl[orow*64 + (((kk<<2)|h) ^ (orow & 7))*8];
                acc[j] = __builtin_amdgcn_mfma_f32_16x16x32_bf16(a, bfr, acc[j], 0, 0, 0);
            }
        }
        __syncthreads();
    }

    int mbase = m0 + w*16 + (l >> 4)*4;
    if (mode == 0) {
        #pragma unroll
        for (int j = 0; j < 4; ++j) {
            int o = o0 + j*16 + (l & 15);
            float bi = bias[o];
            #pragma unroll
            for (int r = 0; r < 4; ++r) {
                float v = acc[j][r] + bi;
                if (relu) v = fmaxf(v, 0.f);
                Ybf[(size_t)(mbase + r)*rowStride + colOff + o] = f2bf(v);
            }
        }
    } else {
        int b = mbase >> 10, ml = mbase & 1023;
        #pragma unroll
        for (int j = 0; j < 4; ++j) {
            int o = o0 + j*16 + (l & 15);
            float bi = bias[o];
            float4 sv = make_float4(acc[j][0]+bi, acc[j][1]+bi, acc[j][2]+bi, acc[j][3]+bi);
            *(float4*)&Yf[((size_t)(b*256 + o))*1024 + ml] = sv;
        }
    }
}

// ---------------------------------------------------------------------------
extern "C" void kernel_launch(void* const* d_in, const int* in_sizes, int n_in,
                              void* d_out, int out_size, void* d_ws, size_t ws_size,
                              hipStream_t stream)
{
    (void)in_sizes; (void)n_in; (void)out_size; (void)ws_size;
    const float* pc        = (const float*)d_in[0];
    const float* seed_xyz  = (const float*)d_in[1];
    const float* seed_feat = (const float*)d_in[2];
    const float* pts       = (const float*)d_in[3];
    const float* feat      = (const float*)d_in[4];
    const float* ln_g      = (const float*)d_in[5];
    const float* ln_b      = (const float*)d_in[6];
    const float* pw1       = (const float*)d_in[7];
    const float* pb1       = (const float*)d_in[8];
    const float* pw2       = (const float*)d_in[9];
    const float* pb2       = (const float*)d_in[10];
    const float* fw1       = (const float*)d_in[11];
    const float* fb1       = (const float*)d_in[12];
    const float* fw2       = (const float*)d_in[13];
    const float* fb2       = (const float*)d_in[14];
    float* out = (float*)d_out;

    char* ws = (char*)d_ws;
    float*          part  = (float*)(ws + OFF_PART);
    float*          rad   = (float*)(ws + OFF_RAD);
    int*            idx   = (int*)(ws + OFF_IDX);
    float*          G     = (float*)(ws + OFF_G);
    unsigned short* xln   = (unsigned short*)(ws + OFF_XLN);
    unsigned short* fused = (unsigned short*)(ws + OFF_FUSED);
    unsigned short* h2    = (unsigned short*)(ws + OFF_H2);
    unsigned short* Wb1   = (unsigned short*)(ws + OFF_WB1);
    unsigned short* Wcat  = (unsigned short*)(ws + OFF_WCAT);
    unsigned short* Wb4   = (unsigned short*)(ws + OFF_WB4);
    float*          bc    = (float*)(ws + OFF_BC);

    k_pre<<<832, 256, 0, stream>>>(pc, pw1, pw2, pb2, fw1, fb1, fw2,
                                   Wb1, Wcat, Wb4, bc, part);
    k_cs_rad<<<64, 256, 0, stream>>>(pc, part, rad);
    k_nn<<<512, 256, 0, stream>>>(seed_xyz, pts, part, rad, idx);
    k_gather_tsf<<<4096, 256, 0, stream>>>(feat, idx, seed_feat, G, fused);
    k_ln_fused<<<dim3(M_/32, B_), 256, 0, stream>>>(G, ln_g, ln_b, xln);
    // gemm1: fused[:,256:512] = relu(pw1 @ xln + pb1)
    k_gemm_mfma<<<dim3(64, 4), 256, 0, stream>>>(xln, Wb1, pb1, 768, 1, 0, fused, 512, 256, nullptr);
    // gemm3': h2 = relu(Wcat @ fused + bc)
    k_gemm_mfma<<<dim3(64, 4), 256, 0, stream>>>(fused, Wcat, bc, 512, 1, 0, h2, 256, 0, nullptr);
    // gemm4: out = fw2 @ h2 + fb2 -> f32 [B][256][M]
    k_gemm_mfma<<<dim3(64, 4), 256, 0, stream>>>(h2, Wb4, fb2, 256, 0, 1, nullptr, 0, 0, out);
}